// Round 3
// baseline (155.434 us; speedup 1.0000x reference)
//
#include <hip/hip_runtime.h>
#include <stdint.h>

typedef unsigned short u16;
typedef unsigned int   u32;
typedef __attribute__((ext_vector_type(8))) short bhalf8;   // 8 bf16 = 4 VGPRs
typedef __attribute__((ext_vector_type(4))) float f32x4;

#define B_ROWS 4096
#define I_DIM  1024
#define O_DIM  1024
#define N_D    6
#define K_LEG  (I_DIM * N_D)   /* 6144 */

#define BM 128
#define BN 128
#define BK 32
#define NSPLIT 4

// float -> bf16 round-to-nearest-even
__device__ __forceinline__ u16 f2b(float f) {
  u32 u = __float_as_uint(f);
  return (u16)((u + 0x7fffu + ((u >> 16) & 1u)) >> 16);
}

// async global->LDS, 16B per lane; LDS dest = wave-uniform base + lane*16
__device__ __forceinline__ void gld_lds16(const void* g, void* l) {
  __builtin_amdgcn_global_load_lds(
      (const __attribute__((address_space(1))) u32*)(uintptr_t)g,
      (__attribute__((address_space(3))) u32*)(u32)(uintptr_t)l, 16, 0, 0);
}

// ---- prep (fused): Bb[o][i] = bf16(bw[i][o]);  Bl[o][i*6+d] = bf16(lw[i][o][d]) ----
__global__ void k_prep_w(const float* __restrict__ bw, const float* __restrict__ lw,
                         u16* __restrict__ Bb, u16* __restrict__ Bl) {
  int j = blockIdx.x * 256 + threadIdx.x;   // j = o*1024 + i
  int o = j >> 10, i = j & 1023;
  Bb[j] = f2b(bw[i * O_DIM + o]);
  const float* s = lw + ((size_t)i * O_DIM + o) * N_D;  // 24B-aligned
  float2 a = *(const float2*)(s);
  float2 b = *(const float2*)(s + 2);
  float2 c = *(const float2*)(s + 4);
  u32* d = (u32*)(Bl + (size_t)o * K_LEG + (size_t)i * N_D); // 4B-aligned, coalesced
  d[0] = (u32)f2b(a.x) | ((u32)f2b(a.y) << 16);
  d[1] = (u32)f2b(b.x) | ((u32)f2b(b.y) << 16);
  d[2] = (u32)f2b(c.x) | ((u32)f2b(c.y) << 16);
}

// ---- prep: per-row min/max, Legendre basis, x*P_d -> bf16 ----
__global__ void k_prep_basis(const float* __restrict__ x,
                             u16* __restrict__ Ab, u16* __restrict__ Al) {
  int b = blockIdx.x;
  int t = threadIdx.x;    // 256 threads, 4 elems each
  float4 v = ((const float4*)(x + (size_t)b * I_DIM))[t];
  float mn = fminf(fminf(v.x, v.y), fminf(v.z, v.w));
  float mx = fmaxf(fmaxf(v.x, v.y), fmaxf(v.z, v.w));
  #pragma unroll
  for (int off = 32; off > 0; off >>= 1) {
    mn = fminf(mn, __shfl_xor(mn, off, 64));
    mx = fmaxf(mx, __shfl_xor(mx, off, 64));
  }
  __shared__ float smn[4], smx[4];
  if ((t & 63) == 0) { smn[t >> 6] = mn; smx[t >> 6] = mx; }
  __syncthreads();
  mn = fminf(fminf(smn[0], smn[1]), fminf(smn[2], smn[3]));
  mx = fmaxf(fmaxf(smx[0], smx[1]), fmaxf(smx[2], smx[3]));
  float sc = 2.0f / (mx - mn + 1e-7f);

  float xs[4] = {v.x, v.y, v.z, v.w};
  u32 lb[12];
  #pragma unroll
  for (int e = 0; e < 4; ++e) {
    float xv = xs[e];
    float xn = (xv - mn) * sc - 1.0f;
    float p0 = 1.0f, p1 = xn;
    float p2 = (3.0f * xn * p1 - 1.0f * p0) * (1.0f / 2.0f);
    float p3 = (5.0f * xn * p2 - 2.0f * p1) * (1.0f / 3.0f);
    float p4 = (7.0f * xn * p3 - 3.0f * p2) * (1.0f / 4.0f);
    float p5 = (9.0f * xn * p4 - 4.0f * p3) * (1.0f / 5.0f);
    lb[e * 3 + 0] = (u32)f2b(xv * p0) | ((u32)f2b(xv * p1) << 16);
    lb[e * 3 + 1] = (u32)f2b(xv * p2) | ((u32)f2b(xv * p3) << 16);
    lb[e * 3 + 2] = (u32)f2b(xv * p4) | ((u32)f2b(xv * p5) << 16);
  }
  u32 a0 = (u32)f2b(xs[0]) | ((u32)f2b(xs[1]) << 16);
  u32 a1 = (u32)f2b(xs[2]) | ((u32)f2b(xs[3]) << 16);
  *(uint2*)(Ab + (size_t)b * I_DIM + t * 4) = make_uint2(a0, a1);
  uint4* dl = (uint4*)(Al + (size_t)b * K_LEG + t * 24);
  dl[0] = make_uint4(lb[0], lb[1], lb[2], lb[3]);
  dl[1] = make_uint4(lb[4], lb[5], lb[6], lb[7]);
  dl[2] = make_uint4(lb[8], lb[9], lb[10], lb[11]);
}

// ---- fused split-K=4 GEMM: 128x128 tile, 4 waves x (4x4 frags), LDS XOR-swizzle ----
// split 0: base(K=1024,32 steps) -> silu(acc) -> leg [0,24)
// splits 1..3: leg [24+56(s-1), 24+56s)
// all atomically add into zeroed out[]
__global__ __launch_bounds__(256, 4) void k_gemm(
    const u16* __restrict__ Ab, const u16* __restrict__ Bb,
    const u16* __restrict__ Al, const u16* __restrict__ Bl,
    float* __restrict__ out) {
  __shared__ alignas(16) u16 As[BM * BK];
  __shared__ alignas(16) u16 Bs[BN * BK];

  const int tid  = threadIdx.x;
  const int wave = tid >> 6;
  const int lane = tid & 63;
  const int wr = wave >> 1;            // 0..1: 64-row band
  const int wc = wave & 1;             // 0..1: 64-col band

  // XCD swizzle over 1024 blocks (1024%8==0 -> bijective); all 4 splits of a
  // tile on one XCD; XCD c owns column panel by==c (B panel 1.75MB, L2-resident)
  int bid  = blockIdx.x;
  int nb   = (bid & 7) * 128 + (bid >> 3);
  const int split = nb & 3;
  const int tile  = nb >> 2;           // 0..255
  const int bx = tile & 31;            // M-tile 0..31
  const int by = tile >> 5;            // N-tile 0..7
  const size_t brow = (size_t)bx * BM;
  const size_t bcol = (size_t)by * BN;

  // staging: lane l covers (row = l>>2, chunk = l&3) of a 16-row group.
  // LDS XOR-swizzle: LDS position (row, c) holds global chunk c ^ ((row>>1)&3)
  // (involution on the chunk bits; LDS dest stays linear for global_load_lds).
  const int srow = lane >> 2;
  const int scol = (((lane & 3) ^ ((lane >> 3) & 3)) * 8);   // swizzled source chunk
  const int kg   = lane >> 4;          // frag k-group 0..3
  const int rr   = lane & 15;          // frag row/col 0..15
  const int kgx  = kg ^ ((rr >> 1) & 3);  // swizzled read chunk (per-thread const)

  f32x4 acc[4][4] = {};
  const bhalf8* Asv = (const bhalf8*)As;
  const bhalf8* Bsv = (const bhalf8*)Bs;

  auto run_phase = [&](const u16* __restrict__ A, const u16* __restrict__ Bt,
                       int ldk, int k0, int k1) {
    const u16* ga = A + (brow + (size_t)(wave * 32 + srow)) * ldk + k0 * BK + scol;
    const u16* gb = Bt + (bcol + (size_t)(wave * 32 + srow)) * ldk + k0 * BK + scol;
    const size_t rstep = (size_t)16 * ldk;
    for (int kt = k0; kt < k1; ++kt) {
      // stage A tile (128x32): wave w -> rows [32w, 32w+32)
      gld_lds16(ga,         (void*)(As + wave * 32 * BK));
      gld_lds16(ga + rstep, (void*)(As + (wave * 32 + 16) * BK));
      // stage B^T tile (128x32)
      gld_lds16(gb,         (void*)(Bs + wave * 32 * BK));
      gld_lds16(gb + rstep, (void*)(Bs + (wave * 32 + 16) * BK));
      ga += BK; gb += BK;
      __syncthreads();
      bhalf8 af[4], bf[4];
      #pragma unroll
      for (int m = 0; m < 4; ++m) af[m] = Asv[(wr * 64 + m * 16 + rr) * (BK / 8) + kgx];
      #pragma unroll
      for (int n = 0; n < 4; ++n) bf[n] = Bsv[(wc * 64 + n * 16 + rr) * (BK / 8) + kgx];
      #pragma unroll
      for (int m = 0; m < 4; ++m)
        #pragma unroll
        for (int n = 0; n < 4; ++n)
          acc[m][n] = __builtin_amdgcn_mfma_f32_16x16x32_bf16(af[m], bf[n], acc[m][n], 0, 0, 0);
      __syncthreads();
    }
  };

  if (split == 0) {
    run_phase(Ab, Bb, I_DIM, 0, I_DIM / BK);   // base GEMM, 32 K-steps
    #pragma unroll
    for (int m = 0; m < 4; ++m)
      #pragma unroll
      for (int n = 0; n < 4; ++n)
        #pragma unroll
        for (int j = 0; j < 4; ++j) {
          float v = acc[m][n][j];
          acc[m][n][j] = v / (1.0f + __expf(-v));
        }
    run_phase(Al, Bl, K_LEG, 0, 24);           // leg [0,24)
  } else {
    run_phase(Al, Bl, K_LEG, 24 + 56 * (split - 1), 24 + 56 * split);
  }

  // C/D layout per 16x16 frag: col = lane&15, row = (lane>>4)*4 + j
  #pragma unroll
  for (int m = 0; m < 4; ++m)
    #pragma unroll
    for (int n = 0; n < 4; ++n) {
      const size_t r0 = brow + wr * 64 + m * 16 + kg * 4;
      const size_t c  = bcol + wc * 64 + n * 16 + rr;
      #pragma unroll
      for (int j = 0; j < 4; ++j)
        unsafeAtomicAdd(&out[(r0 + j) * O_DIM + c], acc[m][n][j]);
    }
}

extern "C" void kernel_launch(void* const* d_in, const int* in_sizes, int n_in,
                              void* d_out, int out_size, void* d_ws, size_t ws_size,
                              hipStream_t stream) {
  const float* x  = (const float*)d_in[0];   // [4096][1024]
  const float* bw = (const float*)d_in[1];   // [1024][1024]
  const float* lw = (const float*)d_in[2];   // [1024][1024][6]
  float* out = (float*)d_out;                // [4096][1024]

  char* w = (char*)d_ws;
  u16* Ab = (u16*)(w);                                  //  8 MiB [4096][1024]
  u16* Al = (u16*)(w + (size_t)8  * 1024 * 1024);       // 48 MiB [4096][6144]
  u16* Bb = (u16*)(w + (size_t)56 * 1024 * 1024);       //  2 MiB [1024][1024]
  u16* Bl = (u16*)(w + (size_t)58 * 1024 * 1024);       // 12 MiB [1024][6144]

  hipMemsetAsync(d_out, 0, (size_t)out_size * sizeof(float), stream);
  k_prep_w    <<<dim3((O_DIM * I_DIM) / 256), 256, 0, stream>>>(bw, lw, Bb, Bl);
  k_prep_basis<<<dim3(B_ROWS), 256, 0, stream>>>(x, Ab, Al);
  k_gemm      <<<dim3(NSPLIT * (B_ROWS / BM) * (O_DIM / BN)), 256, 0, stream>>>(Ab, Bb, Al, Bl, out);
}

// Round 4
// 151.573 us; speedup vs baseline: 1.0255x; 1.0255x over previous
//
#include <hip/hip_runtime.h>
#include <stdint.h>

typedef unsigned short u16;
typedef unsigned int   u32;
typedef __attribute__((ext_vector_type(8))) short bhalf8;   // 8 bf16 = 4 VGPRs
typedef __attribute__((ext_vector_type(4))) float f32x4;

#define B_ROWS 4096
#define I_DIM  1024
#define O_DIM  1024
#define N_D    6
#define K_LEG  (I_DIM * N_D)   /* 6144 */

#define BM 256
#define BN 256
#define BK 32
#define NU 56                   /* K-tiles per split (224 total / 4 splits) */
#define SLOT_BYTES 32768        /* A 16KB + B 16KB */
#define LDS_BYTES  131072       /* 4-slot ring */

// float -> bf16 round-to-nearest-even
__device__ __forceinline__ u16 f2b(float f) {
  u32 u = __float_as_uint(f);
  return (u16)((u + 0x7fffu + ((u >> 16) & 1u)) >> 16);
}

// async global->LDS, 16B per lane; LDS dest = wave-uniform base + lane*16
__device__ __forceinline__ void gld_lds16(const void* g, void* l) {
  __builtin_amdgcn_global_load_lds(
      (const __attribute__((address_space(1))) u32*)(uintptr_t)g,
      (__attribute__((address_space(3))) u32*)(u32)(uintptr_t)l, 16, 0, 0);
}

// ---- prep (fused): Bb[o][i] = bf16(bw[i][o]);  Bl[o][i*6+d] = bf16(lw[i][o][d]) ----
__global__ void k_prep_w(const float* __restrict__ bw, const float* __restrict__ lw,
                         u16* __restrict__ Bb, u16* __restrict__ Bl) {
  int j = blockIdx.x * 256 + threadIdx.x;   // j = o*1024 + i
  int o = j >> 10, i = j & 1023;
  Bb[j] = f2b(bw[i * O_DIM + o]);
  const float* s = lw + ((size_t)i * O_DIM + o) * N_D;  // 24B-aligned
  float2 a = *(const float2*)(s);
  float2 b = *(const float2*)(s + 2);
  float2 c = *(const float2*)(s + 4);
  u32* d = (u32*)(Bl + (size_t)o * K_LEG + (size_t)i * N_D); // coalesced writes
  d[0] = (u32)f2b(a.x) | ((u32)f2b(a.y) << 16);
  d[1] = (u32)f2b(b.x) | ((u32)f2b(b.y) << 16);
  d[2] = (u32)f2b(c.x) | ((u32)f2b(c.y) << 16);
}

// ---- prep: per-row min/max, Legendre basis, x*P_d -> bf16 ----
__global__ void k_prep_basis(const float* __restrict__ x,
                             u16* __restrict__ Ab, u16* __restrict__ Al) {
  int b = blockIdx.x;
  int t = threadIdx.x;    // 256 threads, 4 elems each
  float4 v = ((const float4*)(x + (size_t)b * I_DIM))[t];
  float mn = fminf(fminf(v.x, v.y), fminf(v.z, v.w));
  float mx = fmaxf(fmaxf(v.x, v.y), fmaxf(v.z, v.w));
  #pragma unroll
  for (int off = 32; off > 0; off >>= 1) {
    mn = fminf(mn, __shfl_xor(mn, off, 64));
    mx = fmaxf(mx, __shfl_xor(mx, off, 64));
  }
  __shared__ float smn[4], smx[4];
  if ((t & 63) == 0) { smn[t >> 6] = mn; smx[t >> 6] = mx; }
  __syncthreads();
  mn = fminf(fminf(smn[0], smn[1]), fminf(smn[2], smn[3]));
  mx = fmaxf(fmaxf(smx[0], smx[1]), fmaxf(smx[2], smx[3]));
  float sc = 2.0f / (mx - mn + 1e-7f);

  float xs[4] = {v.x, v.y, v.z, v.w};
  u32 lb[12];
  #pragma unroll
  for (int e = 0; e < 4; ++e) {
    float xv = xs[e];
    float xn = (xv - mn) * sc - 1.0f;
    float p0 = 1.0f, p1 = xn;
    float p2 = (3.0f * xn * p1 - 1.0f * p0) * (1.0f / 2.0f);
    float p3 = (5.0f * xn * p2 - 2.0f * p1) * (1.0f / 3.0f);
    float p4 = (7.0f * xn * p3 - 3.0f * p2) * (1.0f / 4.0f);
    float p5 = (9.0f * xn * p4 - 4.0f * p3) * (1.0f / 5.0f);
    lb[e * 3 + 0] = (u32)f2b(xv * p0) | ((u32)f2b(xv * p1) << 16);
    lb[e * 3 + 1] = (u32)f2b(xv * p2) | ((u32)f2b(xv * p3) << 16);
    lb[e * 3 + 2] = (u32)f2b(xv * p4) | ((u32)f2b(xv * p5) << 16);
  }
  u32 a0 = (u32)f2b(xs[0]) | ((u32)f2b(xs[1]) << 16);
  u32 a1 = (u32)f2b(xs[2]) | ((u32)f2b(xs[3]) << 16);
  *(uint2*)(Ab + (size_t)b * I_DIM + t * 4) = make_uint2(a0, a1);
  uint4* dl = (uint4*)(Al + (size_t)b * K_LEG + t * 24);
  dl[0] = make_uint4(lb[0], lb[1], lb[2], lb[3]);
  dl[1] = make_uint4(lb[4], lb[5], lb[6], lb[7]);
  dl[2] = make_uint4(lb[8], lb[9], lb[10], lb[11]);
}

// ---- fused split-K=4 GEMM: 256x256 tile, 8 waves, 4-slot LDS ring, counted vmcnt ----
// split 0: base(32 K-tiles) -> silu(acc) -> leg [0,24)
// splits 1..3: leg [24+56(s-1), 24+56s)
__global__ __launch_bounds__(512, 2) void k_gemm(
    const u16* __restrict__ Ab, const u16* __restrict__ Bb,
    const u16* __restrict__ Al, const u16* __restrict__ Bl,
    float* __restrict__ out) {
  extern __shared__ char lds[];

  const int tid  = threadIdx.x;
  const int wave = tid >> 6;
  const int lane = tid & 63;
  const int wm = wave >> 2;            // 0..1: 128-row band
  const int wn = wave & 3;             // 0..3: 64-col band
  const int rr = lane & 15;
  const int kg = lane >> 4;

  // bid = bx*16 + by*4 + split: default %8 XCD round-robin puts all 16 bx-blocks
  // of a (by,split) pair on one XCD -> B panel (0.9MB) L2-resident.
  const int bid   = blockIdx.x;        // 256 blocks = 1/CU, all co-resident
  const int bx    = bid >> 4;          // 0..15
  const int by    = (bid >> 2) & 3;    // 0..3
  const int split = bid & 3;
  const size_t brow = (size_t)bx * BM;
  const size_t bcol = (size_t)by * BN;
  const bool s0 = (split == 0);
  const int legbase = s0 ? 0 : (24 + 56 * (split - 1));

  // staging per-thread coords: thread t covers (row = q*128 + t/4, chunk = t&3),
  // source chunk pre-swizzled by row&3 (involution; LDS dest stays linear).
  const int r4 = tid >> 2;
  const size_t cs = (size_t)((((tid & 3) ^ (r4 & 3))) * 8);
  const size_t ar0 = brow + r4,        ar1 = brow + 128 + r4;
  const size_t bc0 = bcol + r4,        bc1 = bcol + 128 + r4;
  char* const l0 = lds + (u32)wave * 1024;

  auto stage = [&](int v) {
    const u16 *sa, *sb; size_t ldk, koff;
    if (s0 && v < 32) { sa = Ab; sb = Bb; ldk = I_DIM; koff = (size_t)v * BK; }
    else {
      size_t lv = s0 ? (size_t)(v - 32) : (size_t)(legbase + v);
      sa = Al; sb = Bl; ldk = K_LEG; koff = lv * BK;
    }
    char* d = l0 + (size_t)(v & 3) * SLOT_BYTES;
    gld_lds16(sa + ar0 * ldk + koff + cs, d);
    gld_lds16(sa + ar1 * ldk + koff + cs, d + 8192);
    gld_lds16(sb + bc0 * ldk + koff + cs, d + 16384);
    gld_lds16(sb + bc1 * ldk + koff + cs, d + 24576);
  };

  // frag-read per-thread byte offsets (swizzled: chunk kg ^ (row&3), row&3 == rr&3)
  const u32 axor  = (u32)((kg ^ (rr & 3)) * 16);
  const u32 abase = (u32)((wm * 128 + rr) * 64) + axor;
  const u32 bbase = 16384u + (u32)((wn * 64 + rr) * 64) + axor;

  f32x4 acc[8][4] = {};

  stage(0); stage(1); stage(2);   // 12 loads in flight

#define KITER(u, DO_STAGE, VM)  do {                                          \
    if (DO_STAGE) stage((u) + 3);                                             \
    asm volatile("s_waitcnt vmcnt(" #VM ")" ::: "memory");                    \
    __builtin_amdgcn_s_barrier();                                             \
    asm volatile("" ::: "memory");                                            \
    const char* p_ = lds + (size_t)((u) & 3) * SLOT_BYTES;                    \
    bhalf8 af_[8], bf_[4];                                                    \
    _Pragma("unroll")                                                         \
    for (int n = 0; n < 4; ++n) bf_[n] = *(const bhalf8*)(p_ + bbase + n * 1024); \
    _Pragma("unroll")                                                         \
    for (int m = 0; m < 8; ++m) af_[m] = *(const bhalf8*)(p_ + abase + m * 1024); \
    __builtin_amdgcn_s_setprio(1);                                            \
    _Pragma("unroll")                                                         \
    for (int m = 0; m < 8; ++m)                                               \
      _Pragma("unroll")                                                       \
      for (int n = 0; n < 4; ++n)                                             \
        acc[m][n] = __builtin_amdgcn_mfma_f32_16x16x32_bf16(af_[m], bf_[n], acc[m][n], 0, 0, 0); \
    __builtin_amdgcn_s_setprio(0);                                            \
    asm volatile("s_waitcnt lgkmcnt(0)" ::: "memory");                        \
    __builtin_amdgcn_s_barrier();                                             \
  } while (0)

  for (int u = 0; u < NU - 3; ++u) {   // u = 0..52, always stages u+3 (<= 55)
    if (s0 && u == 32) {               // base done -> silu in registers
      #pragma unroll
      for (int m = 0; m < 8; ++m)
        #pragma unroll
        for (int n = 0; n < 4; ++n)
          #pragma unroll
          for (int j = 0; j < 4; ++j) {
            float v = acc[m][n][j];
            acc[m][n][j] = v / (1.0f + __expf(-v));
          }
    }
    KITER(u, true, 12);
  }
  KITER(53, false, 8);
  KITER(54, false, 4);
  KITER(55, false, 0);
#undef KITER

  // C/D layout per 16x16 frag: col = lane&15, row = (lane>>4)*4 + j
  #pragma unroll
  for (int m = 0; m < 8; ++m)
    #pragma unroll
    for (int n = 0; n < 4; ++n) {
      const size_t r0 = brow + wm * 128 + m * 16 + kg * 4;
      const size_t c  = bcol + wn * 64 + n * 16 + rr;
      #pragma unroll
      for (int j = 0; j < 4; ++j)
        unsafeAtomicAdd(&out[(r0 + j) * O_DIM + c], acc[m][n][j]);
    }
}

extern "C" void kernel_launch(void* const* d_in, const int* in_sizes, int n_in,
                              void* d_out, int out_size, void* d_ws, size_t ws_size,
                              hipStream_t stream) {
  const float* x  = (const float*)d_in[0];   // [4096][1024]
  const float* bw = (const float*)d_in[1];   // [1024][1024]
  const float* lw = (const float*)d_in[2];   // [1024][1024][6]
  float* out = (float*)d_out;                // [4096][1024]

  char* w = (char*)d_ws;
  u16* Ab = (u16*)(w);                                  //  8 MiB [4096][1024]
  u16* Al = (u16*)(w + (size_t)8  * 1024 * 1024);       // 48 MiB [4096][6144]
  u16* Bb = (u16*)(w + (size_t)56 * 1024 * 1024);       //  2 MiB [1024][1024]
  u16* Bl = (u16*)(w + (size_t)58 * 1024 * 1024);       // 12 MiB [1024][6144]

  hipFuncSetAttribute((const void*)k_gemm,
                      hipFuncAttributeMaxDynamicSharedMemorySize, LDS_BYTES);

  hipMemsetAsync(d_out, 0, (size_t)out_size * sizeof(float), stream);
  k_prep_w    <<<dim3((O_DIM * I_DIM) / 256), 256, 0, stream>>>(bw, lw, Bb, Bl);
  k_prep_basis<<<dim3(B_ROWS), 256, 0, stream>>>(x, Ab, Al);
  k_gemm      <<<dim3(4 * (B_ROWS / BM) * (O_DIM / BN)), 512, LDS_BYTES, stream>>>(Ab, Bb, Al, Bl, out);
}

// Round 5
// 118.040 us; speedup vs baseline: 1.3168x; 1.2841x over previous
//
#include <hip/hip_runtime.h>
#include <stdint.h>

typedef unsigned short u16;
typedef unsigned int   u32;
typedef __attribute__((ext_vector_type(8))) short bhalf8;   // 8 bf16 = 4 VGPRs
typedef __attribute__((ext_vector_type(4))) float f32x4;

#define B_ROWS 4096
#define I_DIM  1024
#define O_DIM  1024
#define N_D    6
#define K_LEG  (I_DIM * N_D)   /* 6144 */

#define BM 256
#define BN 256
#define BK 32
#define NU 56                   /* K-tiles per split (224 total / 4 splits) */
#define SLOT_BYTES 32768        /* A 16KB + B 16KB */
#define LDS_BYTES  131072       /* 4-slot ring */

// float -> bf16 round-to-nearest-even
__device__ __forceinline__ u16 f2b(float f) {
  u32 u = __float_as_uint(f);
  return (u16)((u + 0x7fffu + ((u >> 16) & 1u)) >> 16);
}

// async global->LDS, 16B per lane; LDS dest = wave-uniform base + lane*16
__device__ __forceinline__ void gld_lds16(const void* g, void* l) {
  __builtin_amdgcn_global_load_lds(
      (const __attribute__((address_space(1))) u32*)(uintptr_t)g,
      (__attribute__((address_space(3))) u32*)(u32)(uintptr_t)l, 16, 0, 0);
}

// ---- prep: Bb[o][i] = bf16(bw[i][o]) via LDS 32x32 tile (both sides coalesced) ----
__global__ void k_prep_bbT(const float* __restrict__ bw, u16* __restrict__ Bb) {
  __shared__ float t[32][33];
  const int bx = blockIdx.x & 31, by = blockIdx.x >> 5;   // 1024 blocks
  const int i0 = by * 32, o0 = bx * 32;
  const int c = threadIdx.x & 31, r0 = threadIdx.x >> 5;  // 8 rows/pass
  #pragma unroll
  for (int k = 0; k < 4; ++k) {
    int r = r0 + k * 8;
    t[r][c] = bw[(size_t)(i0 + r) * O_DIM + o0 + c];
  }
  __syncthreads();
  #pragma unroll
  for (int k = 0; k < 4; ++k) {
    int r = r0 + k * 8;
    Bb[(size_t)(o0 + r) * I_DIM + i0 + c] = f2b(t[c][r]);
  }
}

// ---- prep: Bl[o][i*6+d] = bf16(lw[i][o][d]) via LDS tile of 32x32 24B-microvectors ----
#define RS 201
__global__ void k_prep_blT(const float* __restrict__ lw, u16* __restrict__ Bl) {
  __shared__ float t[32 * RS];
  const int bx = blockIdx.x & 31, by = blockIdx.x >> 5;   // 1024 blocks
  const int i0 = by * 32, o0 = bx * 32;
  // read: 32 i-rows x 192 floats (o_local*6+d), float4-coalesced
  for (int q = threadIdx.x; q < 32 * 48; q += 256) {
    int ri = q / 48, s4 = q % 48;
    float4 v = *(const float4*)(lw + (size_t)(i0 + ri) * (O_DIM * N_D) + o0 * N_D + s4 * 4);
    float* p = t + ri * RS + s4 * 4;
    p[0] = v.x; p[1] = v.y; p[2] = v.z; p[3] = v.w;
  }
  __syncthreads();
  // write: 32 o-rows x 96 u32 (2 bf16 each), coalesced
  for (int q = threadIdx.x; q < 32 * 96; q += 256) {
    int ro = q / 96, k = q % 96;
    int e0 = 2 * k, e1 = 2 * k + 1;
    float v0 = t[(e0 / 6) * RS + ro * 6 + (e0 % 6)];
    float v1 = t[(e1 / 6) * RS + ro * 6 + (e1 % 6)];
    u32* dst = (u32*)(Bl + (size_t)(o0 + ro) * K_LEG + i0 * N_D);
    dst[k] = (u32)f2b(v0) | ((u32)f2b(v1) << 16);
  }
}

// ---- prep: per-row min/max, Legendre basis, x*P_d -> bf16 ----
__global__ void k_prep_basis(const float* __restrict__ x,
                             u16* __restrict__ Ab, u16* __restrict__ Al) {
  int b = blockIdx.x;
  int t = threadIdx.x;    // 256 threads, 4 elems each
  float4 v = ((const float4*)(x + (size_t)b * I_DIM))[t];
  float mn = fminf(fminf(v.x, v.y), fminf(v.z, v.w));
  float mx = fmaxf(fmaxf(v.x, v.y), fmaxf(v.z, v.w));
  #pragma unroll
  for (int off = 32; off > 0; off >>= 1) {
    mn = fminf(mn, __shfl_xor(mn, off, 64));
    mx = fmaxf(mx, __shfl_xor(mx, off, 64));
  }
  __shared__ float smn[4], smx[4];
  if ((t & 63) == 0) { smn[t >> 6] = mn; smx[t >> 6] = mx; }
  __syncthreads();
  mn = fminf(fminf(smn[0], smn[1]), fminf(smn[2], smn[3]));
  mx = fmaxf(fmaxf(smx[0], smx[1]), fmaxf(smx[2], smx[3]));
  float sc = 2.0f / (mx - mn + 1e-7f);

  float xs[4] = {v.x, v.y, v.z, v.w};
  u32 lb[12];
  #pragma unroll
  for (int e = 0; e < 4; ++e) {
    float xv = xs[e];
    float xn = (xv - mn) * sc - 1.0f;
    float p0 = 1.0f, p1 = xn;
    float p2 = (3.0f * xn * p1 - 1.0f * p0) * (1.0f / 2.0f);
    float p3 = (5.0f * xn * p2 - 2.0f * p1) * (1.0f / 3.0f);
    float p4 = (7.0f * xn * p3 - 3.0f * p2) * (1.0f / 4.0f);
    float p5 = (9.0f * xn * p4 - 4.0f * p3) * (1.0f / 5.0f);
    lb[e * 3 + 0] = (u32)f2b(xv * p0) | ((u32)f2b(xv * p1) << 16);
    lb[e * 3 + 1] = (u32)f2b(xv * p2) | ((u32)f2b(xv * p3) << 16);
    lb[e * 3 + 2] = (u32)f2b(xv * p4) | ((u32)f2b(xv * p5) << 16);
  }
  u32 a0 = (u32)f2b(xs[0]) | ((u32)f2b(xs[1]) << 16);
  u32 a1 = (u32)f2b(xs[2]) | ((u32)f2b(xs[3]) << 16);
  *(uint2*)(Ab + (size_t)b * I_DIM + t * 4) = make_uint2(a0, a1);
  uint4* dl = (uint4*)(Al + (size_t)b * K_LEG + t * 24);
  dl[0] = make_uint4(lb[0], lb[1], lb[2], lb[3]);
  dl[1] = make_uint4(lb[4], lb[5], lb[6], lb[7]);
  dl[2] = make_uint4(lb[8], lb[9], lb[10], lb[11]);
}

// ---- fused split-K=4 GEMM: 256x256 tile, 8 waves, 4-slot LDS ring, counted vmcnt ----
// split 0: base(32 K-tiles) -> silu(acc) -> leg [0,24) -> plain store to out
// splits 1..3: leg [24+56(s-1), 24+56s)   -> plain store to P[s-1]
__global__ __launch_bounds__(512, 2) void k_gemm(
    const u16* __restrict__ Ab, const u16* __restrict__ Bb,
    const u16* __restrict__ Al, const u16* __restrict__ Bl,
    float* __restrict__ out, float* __restrict__ P) {
  extern __shared__ char lds[];

  const int tid  = threadIdx.x;
  const int wave = tid >> 6;
  const int lane = tid & 63;
  const int wm = wave >> 2;            // 0..1: 128-row band
  const int wn = wave & 3;             // 0..3: 64-col band
  const int rr = lane & 15;
  const int kg = lane >> 4;

  const int bid   = blockIdx.x;        // 256 blocks = 1/CU, all co-resident
  const int bx    = bid >> 4;          // 0..15
  const int by    = (bid >> 2) & 3;    // 0..3
  const int split = bid & 3;
  const size_t brow = (size_t)bx * BM;
  const size_t bcol = (size_t)by * BN;
  const bool s0 = (split == 0);
  const int legbase = s0 ? 0 : (24 + 56 * (split - 1));

  // staging: thread t covers (row = r4, chunk = t&3) of each 128-row half;
  // source chunk pre-swizzled by (row>>1)&3 (R3-verified 0-conflict key).
  const int r4 = tid >> 2;
  const size_t cs = (size_t)((((tid & 3) ^ ((r4 >> 1) & 3))) * 8);
  const size_t ar0 = brow + r4,        ar1 = brow + 128 + r4;
  const size_t bc0 = bcol + r4,        bc1 = bcol + 128 + r4;
  char* const l0 = lds + (u32)wave * 1024;

  auto stage = [&](int v) {
    const u16 *sa, *sb; size_t ldk, koff;
    if (s0 && v < 32) { sa = Ab; sb = Bb; ldk = I_DIM; koff = (size_t)v * BK; }
    else {
      size_t lv = s0 ? (size_t)(v - 32) : (size_t)(legbase + v);
      sa = Al; sb = Bl; ldk = K_LEG; koff = lv * BK;
    }
    char* d = l0 + (size_t)(v & 3) * SLOT_BYTES;
    gld_lds16(sa + ar0 * ldk + koff + cs, d);
    gld_lds16(sa + ar1 * ldk + koff + cs, d + 8192);
    gld_lds16(sb + bc0 * ldk + koff + cs, d + 16384);
    gld_lds16(sb + bc1 * ldk + koff + cs, d + 24576);
  };

  // frag-read byte offsets: chunk kg ^ ((row>>1)&3); row mod 16 == rr
  const u32 axor  = (u32)((kg ^ ((rr >> 1) & 3)) * 16);
  const u32 abase = (u32)((wm * 128 + rr) * 64) + axor;
  const u32 bbase = 16384u + (u32)((wn * 64 + rr) * 64) + axor;

  f32x4 acc[8][4] = {};

  stage(0); stage(1); stage(2);   // 12 loads in flight

#define KITER(u, DO_STAGE, VM)  do {                                          \
    if (DO_STAGE) stage((u) + 3);                                             \
    asm volatile("s_waitcnt vmcnt(" #VM ")" ::: "memory");                    \
    __builtin_amdgcn_s_barrier();                                             \
    asm volatile("" ::: "memory");                                            \
    const char* p_ = lds + (size_t)((u) & 3) * SLOT_BYTES;                    \
    bhalf8 af_[8], bf_[4];                                                    \
    _Pragma("unroll")                                                         \
    for (int n = 0; n < 4; ++n) bf_[n] = *(const bhalf8*)(p_ + bbase + n * 1024); \
    _Pragma("unroll")                                                         \
    for (int m = 0; m < 8; ++m) af_[m] = *(const bhalf8*)(p_ + abase + m * 1024); \
    __builtin_amdgcn_s_setprio(1);                                            \
    _Pragma("unroll")                                                         \
    for (int m = 0; m < 8; ++m)                                               \
      _Pragma("unroll")                                                       \
      for (int n = 0; n < 4; ++n)                                             \
        acc[m][n] = __builtin_amdgcn_mfma_f32_16x16x32_bf16(af_[m], bf_[n], acc[m][n], 0, 0, 0); \
    __builtin_amdgcn_s_setprio(0);                                            \
    asm volatile("s_waitcnt lgkmcnt(0)" ::: "memory");                        \
    __builtin_amdgcn_s_barrier();                                             \
  } while (0)

  for (int u = 0; u < NU - 3; ++u) {   // u = 0..52, stages u+3 (<= 55)
    if (s0 && u == 32) {               // base done -> silu in registers
      #pragma unroll
      for (int m = 0; m < 8; ++m)
        #pragma unroll
        for (int n = 0; n < 4; ++n)
          #pragma unroll
          for (int j = 0; j < 4; ++j) {
            float v = acc[m][n][j];
            acc[m][n][j] = v / (1.0f + __expf(-v));
          }
    }
    KITER(u, true, 12);
  }
  KITER(53, false, 8);
  KITER(54, false, 4);
  KITER(55, false, 0);
#undef KITER

  // plain stores: split 0 -> out, split s>0 -> partial P[s-1]
  float* dst = s0 ? out : (P + (size_t)(split - 1) * ((size_t)B_ROWS * O_DIM));
  #pragma unroll
  for (int m = 0; m < 8; ++m)
    #pragma unroll
    for (int n = 0; n < 4; ++n) {
      const size_t r0 = brow + wm * 128 + m * 16 + kg * 4;
      const size_t c  = bcol + wn * 64 + n * 16 + rr;
      #pragma unroll
      for (int j = 0; j < 4; ++j)
        dst[(r0 + j) * O_DIM + c] = acc[m][n][j];
    }
}

// ---- final: out += P0 + P1 + P2 (float4) ----
__global__ void k_reduce(float* __restrict__ out, const float* __restrict__ P) {
  const size_t i = (size_t)blockIdx.x * 256 + threadIdx.x;
  const size_t NE = (size_t)B_ROWS * O_DIM / 4;
  float4 a = ((const float4*)out)[i];
  float4 b = ((const float4*)P)[i];
  float4 c = ((const float4*)P)[i + NE];
  float4 d = ((const float4*)P)[i + 2 * NE];
  a.x += b.x + c.x + d.x;  a.y += b.y + c.y + d.y;
  a.z += b.z + c.z + d.z;  a.w += b.w + c.w + d.w;
  ((float4*)out)[i] = a;
}

extern "C" void kernel_launch(void* const* d_in, const int* in_sizes, int n_in,
                              void* d_out, int out_size, void* d_ws, size_t ws_size,
                              hipStream_t stream) {
  const float* x  = (const float*)d_in[0];   // [4096][1024]
  const float* bw = (const float*)d_in[1];   // [1024][1024]
  const float* lw = (const float*)d_in[2];   // [1024][1024][6]
  float* out = (float*)d_out;                // [4096][1024]

  char* w = (char*)d_ws;
  u16*  Ab = (u16*)(w);                                  //  8 MiB [4096][1024]
  u16*  Al = (u16*)(w + (size_t)8   * 1024 * 1024);      // 48 MiB [4096][6144]
  u16*  Bb = (u16*)(w + (size_t)56  * 1024 * 1024);      //  2 MiB [1024][1024]
  u16*  Bl = (u16*)(w + (size_t)58  * 1024 * 1024);      // 12 MiB [1024][6144]
  float* P = (float*)(w + (size_t)72 * 1024 * 1024);     // 48 MiB: 3 x [4096][1024] f32

  hipFuncSetAttribute((const void*)k_gemm,
                      hipFuncAttributeMaxDynamicSharedMemorySize, LDS_BYTES);

  k_prep_bbT  <<<dim3(1024), 256, 0, stream>>>(bw, Bb);
  k_prep_blT  <<<dim3(1024), 256, 0, stream>>>(lw, Bl);
  k_prep_basis<<<dim3(B_ROWS), 256, 0, stream>>>(x, Ab, Al);
  k_gemm      <<<dim3(4 * (B_ROWS / BM) * (O_DIM / BN)), 512, LDS_BYTES, stream>>>(Ab, Bb, Al, Bl, out, P);
  k_reduce    <<<dim3((B_ROWS * O_DIM / 4) / 256), 256, 0, stream>>>(out, P);
}

// Round 6
// 112.766 us; speedup vs baseline: 1.3784x; 1.0468x over previous
//
#include <hip/hip_runtime.h>
#include <stdint.h>

typedef unsigned short u16;
typedef unsigned int   u32;
typedef __attribute__((ext_vector_type(8))) short bhalf8;   // 8 bf16 = 4 VGPRs
typedef __attribute__((ext_vector_type(4))) float f32x4;

#define B_ROWS 4096
#define I_DIM  1024
#define O_DIM  1024
#define N_D    6
#define K_LEG  (I_DIM * N_D)   /* 6144 */

#define BM 256
#define BN 256
#define BK 32
#define NU 56                   /* K-tiles per split (224 total / 4 splits) */
#define SLOT_BYTES 32768        /* A 16KB + B 16KB */
#define LDS_BYTES  131072       /* 4-slot ring */

// float -> bf16 round-to-nearest-even
__device__ __forceinline__ u16 f2b(float f) {
  u32 u = __float_as_uint(f);
  return (u16)((u + 0x7fffu + ((u >> 16) & 1u)) >> 16);
}

// async global->LDS, 16B per lane; LDS dest = wave-uniform base + lane*16
__device__ __forceinline__ void gld_lds16(const void* g, void* l) {
  __builtin_amdgcn_global_load_lds(
      (const __attribute__((address_space(1))) u32*)(uintptr_t)g,
      (__attribute__((address_space(3))) u32*)(u32)(uintptr_t)l, 16, 0, 0);
}

// ---- prep (merged): blocks [0,1024): Bb[o][i] = bf16(bw[i][o]) via 32x32 LDS tile
//                     blocks [1024,2048): Bl[o][i*6+d] = bf16(lw[i][o][d]) ----
#define RS 201
__global__ void k_prep_w(const float* __restrict__ bw, const float* __restrict__ lw,
                         u16* __restrict__ Bb, u16* __restrict__ Bl) {
  __shared__ float t[32 * RS];
  if (blockIdx.x < 1024) {
    const int bx = blockIdx.x & 31, by = blockIdx.x >> 5;
    const int i0 = by * 32, o0 = bx * 32;
    const int c = threadIdx.x & 31, r0 = threadIdx.x >> 5;
    #pragma unroll
    for (int k = 0; k < 4; ++k) {
      int r = r0 + k * 8;
      t[r * 33 + c] = bw[(size_t)(i0 + r) * O_DIM + o0 + c];
    }
    __syncthreads();
    #pragma unroll
    for (int k = 0; k < 4; ++k) {
      int r = r0 + k * 8;
      Bb[(size_t)(o0 + r) * I_DIM + i0 + c] = f2b(t[c * 33 + r]);
    }
  } else {
    const int blk = blockIdx.x - 1024;
    const int bx = blk & 31, by = blk >> 5;
    const int i0 = by * 32, o0 = bx * 32;
    for (int q = threadIdx.x; q < 32 * 48; q += 256) {
      int ri = q / 48, s4 = q % 48;
      float4 v = *(const float4*)(lw + (size_t)(i0 + ri) * (O_DIM * N_D) + o0 * N_D + s4 * 4);
      float* p = t + ri * RS + s4 * 4;
      p[0] = v.x; p[1] = v.y; p[2] = v.z; p[3] = v.w;
    }
    __syncthreads();
    for (int q = threadIdx.x; q < 32 * 96; q += 256) {
      int ro = q / 96, k = q % 96;
      int e0 = 2 * k, e1 = 2 * k + 1;
      float v0 = t[(e0 / 6) * RS + ro * 6 + (e0 % 6)];
      float v1 = t[(e1 / 6) * RS + ro * 6 + (e1 % 6)];
      u32* dst = (u32*)(Bl + (size_t)(o0 + ro) * K_LEG + i0 * N_D);
      dst[k] = (u32)f2b(v0) | ((u32)f2b(v1) << 16);
    }
  }
}

// ---- prep: per-row min/max, Legendre basis, x*P_d -> bf16 ----
__global__ void k_prep_basis(const float* __restrict__ x,
                             u16* __restrict__ Ab, u16* __restrict__ Al) {
  int b = blockIdx.x;
  int t = threadIdx.x;    // 256 threads, 4 elems each
  float4 v = ((const float4*)(x + (size_t)b * I_DIM))[t];
  float mn = fminf(fminf(v.x, v.y), fminf(v.z, v.w));
  float mx = fmaxf(fmaxf(v.x, v.y), fmaxf(v.z, v.w));
  #pragma unroll
  for (int off = 32; off > 0; off >>= 1) {
    mn = fminf(mn, __shfl_xor(mn, off, 64));
    mx = fmaxf(mx, __shfl_xor(mx, off, 64));
  }
  __shared__ float smn[4], smx[4];
  if ((t & 63) == 0) { smn[t >> 6] = mn; smx[t >> 6] = mx; }
  __syncthreads();
  mn = fminf(fminf(smn[0], smn[1]), fminf(smn[2], smn[3]));
  mx = fmaxf(fmaxf(smx[0], smx[1]), fmaxf(smx[2], smx[3]));
  float sc = 2.0f / (mx - mn + 1e-7f);

  float xs[4] = {v.x, v.y, v.z, v.w};
  u32 lb[12];
  #pragma unroll
  for (int e = 0; e < 4; ++e) {
    float xv = xs[e];
    float xn = (xv - mn) * sc - 1.0f;
    float p0 = 1.0f, p1 = xn;
    float p2 = (3.0f * xn * p1 - 1.0f * p0) * (1.0f / 2.0f);
    float p3 = (5.0f * xn * p2 - 2.0f * p1) * (1.0f / 3.0f);
    float p4 = (7.0f * xn * p3 - 3.0f * p2) * (1.0f / 4.0f);
    float p5 = (9.0f * xn * p4 - 4.0f * p3) * (1.0f / 5.0f);
    lb[e * 3 + 0] = (u32)f2b(xv * p0) | ((u32)f2b(xv * p1) << 16);
    lb[e * 3 + 1] = (u32)f2b(xv * p2) | ((u32)f2b(xv * p3) << 16);
    lb[e * 3 + 2] = (u32)f2b(xv * p4) | ((u32)f2b(xv * p5) << 16);
  }
  u32 a0 = (u32)f2b(xs[0]) | ((u32)f2b(xs[1]) << 16);
  u32 a1 = (u32)f2b(xs[2]) | ((u32)f2b(xs[3]) << 16);
  *(uint2*)(Ab + (size_t)b * I_DIM + t * 4) = make_uint2(a0, a1);
  uint4* dl = (uint4*)(Al + (size_t)b * K_LEG + t * 24);
  dl[0] = make_uint4(lb[0], lb[1], lb[2], lb[3]);
  dl[1] = make_uint4(lb[4], lb[5], lb[6], lb[7]);
  dl[2] = make_uint4(lb[8], lb[9], lb[10], lb[11]);
}

// ---- fused split-K=4 GEMM: 256x256 tile, 8 waves, 4-slot ring, m201 2-phase/K-tile ----
// split 0: base(32 K-tiles) -> silu(acc) -> leg [0,24) -> plain store to out
// splits 1..3: leg [24+56(s-1), 24+56s)   -> plain store to P[s-1]
__global__ __launch_bounds__(512, 2) void k_gemm(
    const u16* __restrict__ Ab, const u16* __restrict__ Bb,
    const u16* __restrict__ Al, const u16* __restrict__ Bl,
    float* __restrict__ out, float* __restrict__ P) {
  extern __shared__ char lds[];

  const int tid  = threadIdx.x;
  const int wave = tid >> 6;
  const int lane = tid & 63;
  const int wm = wave >> 2;            // 0..1: 128-row band
  const int wn = wave & 3;             // 0..3: 64-col band
  const int rr = lane & 15;
  const int kg = lane >> 4;

  const int bid   = blockIdx.x;        // 256 blocks = 1/CU, all co-resident
  const int bx    = bid >> 4;          // 0..15
  const int by    = (bid >> 2) & 3;    // 0..3
  const int split = bid & 3;
  const size_t brow = (size_t)bx * BM;
  const size_t bcol = (size_t)by * BN;
  const bool s0 = (split == 0);
  const int legbase = s0 ? 0 : (24 + 56 * (split - 1));

  // staging: thread t covers (row = r4, chunk = t&3) of each 128-row half;
  // source chunk pre-swizzled by (row>>1)&3 (verified 0-conflict key).
  const int r4 = tid >> 2;
  const size_t cs = (size_t)((((tid & 3) ^ ((r4 >> 1) & 3))) * 8);
  char* const l0 = lds + (u32)wave * 1024;

  // incremental staging pointers (rebuilt once at the base->leg boundary)
  const u16 *gA0, *gA1, *gB0, *gB1;
  auto set_ptrs = [&](const u16* A, const u16* Bt, size_t ldk, size_t kt) {
    const size_t ko = kt * BK + cs;
    gA0 = A  + (brow + r4) * ldk + ko;
    gA1 = A  + (brow + 128 + r4) * ldk + ko;
    gB0 = Bt + (bcol + r4) * ldk + ko;
    gB1 = Bt + (bcol + 128 + r4) * ldk + ko;
  };
  if (s0) set_ptrs(Ab, Bb, I_DIM, 0);
  else    set_ptrs(Al, Bl, K_LEG, (size_t)legbase);

  // frag-read byte offsets: chunk kg ^ ((row>>1)&3); row mod 16 == rr
  const u32 axor  = (u32)((kg ^ ((rr >> 1) & 3)) * 16);
  const u32 abase = (u32)((wm * 128 + rr) * 64) + axor;
  const u32 bbase = 16384u + (u32)((wn * 64 + rr) * 64) + axor;

  f32x4 acc[8][4] = {};
  bhalf8 af_[4], af2_[4], bf_[4];

  // prologue: fully stage tiles 0,1,2 (12 loads), advancing pointers each tile
  #pragma unroll
  for (int v = 0; v < 3; ++v) {
    char* d = l0 + (size_t)v * SLOT_BYTES;
    gld_lds16(gA0, d);          gld_lds16(gA1, d + 8192);
    gld_lds16(gB0, d + 16384);  gld_lds16(gB1, d + 24576);
    gA0 += BK; gA1 += BK; gB0 += BK; gB1 += BK;
  }
  asm volatile("s_waitcnt vmcnt(8)" ::: "memory");   // tile 0 landed
  __builtin_amdgcn_s_barrier();

  // Phase 0: reads af[0..3],bf[0..3] of slot u; stage A-halves of u+3; 16 MFMA (m0..3)
#define PH0(u, DO_STAGE) do {                                                 \
    const char* p_ = lds + (size_t)((u) & 3) * SLOT_BYTES;                    \
    _Pragma("unroll")                                                         \
    for (int n = 0; n < 4; ++n) bf_[n] = *(const bhalf8*)(p_ + bbase + n * 1024); \
    _Pragma("unroll")                                                         \
    for (int m = 0; m < 4; ++m) af_[m] = *(const bhalf8*)(p_ + abase + m * 1024); \
    if (DO_STAGE) {                                                           \
      char* d_ = l0 + (size_t)(((u) + 3) & 3) * SLOT_BYTES;                   \
      gld_lds16(gA0, d_); gld_lds16(gA1, d_ + 8192);                          \
    }                                                                         \
    asm volatile("" ::: "memory");                                            \
    __builtin_amdgcn_s_barrier();                                             \
    asm volatile("s_waitcnt lgkmcnt(0)" ::: "memory");                        \
    __builtin_amdgcn_s_setprio(1);                                            \
    _Pragma("unroll")                                                         \
    for (int m = 0; m < 4; ++m)                                               \
      _Pragma("unroll")                                                       \
      for (int n = 0; n < 4; ++n)                                             \
        acc[m][n] = __builtin_amdgcn_mfma_f32_16x16x32_bf16(af_[m], bf_[n], acc[m][n], 0, 0, 0); \
    __builtin_amdgcn_s_setprio(0);                                            \
    __builtin_amdgcn_s_barrier();                                             \
  } while (0)

  // Phase 1: reads af[4..7]; stage B-halves of u+3 + advance; vmcnt(VM) -> tile u+1
  // confirmed; 16 MFMA (m4..7)
#define PH1(u, DO_STAGE, VM) do {                                             \
    const char* p_ = lds + (size_t)((u) & 3) * SLOT_BYTES;                    \
    _Pragma("unroll")                                                         \
    for (int m = 0; m < 4; ++m) af2_[m] = *(const bhalf8*)(p_ + abase + (4 + m) * 1024); \
    if (DO_STAGE) {                                                           \
      char* d_ = l0 + (size_t)(((u) + 3) & 3) * SLOT_BYTES;                   \
      gld_lds16(gB0, d_ + 16384); gld_lds16(gB1, d_ + 24576);                 \
      if (s0 && (u) + 4 == 32) set_ptrs(Al, Bl, K_LEG, 0);                    \
      else { gA0 += BK; gA1 += BK; gB0 += BK; gB1 += BK; }                    \
    }                                                                         \
    asm volatile("s_waitcnt vmcnt(" #VM ")" ::: "memory");                    \
    __builtin_amdgcn_s_barrier();                                             \
    asm volatile("s_waitcnt lgkmcnt(0)" ::: "memory");                        \
    __builtin_amdgcn_s_setprio(1);                                            \
    _Pragma("unroll")                                                         \
    for (int m = 0; m < 4; ++m)                                               \
      _Pragma("unroll")                                                       \
      for (int n = 0; n < 4; ++n)                                             \
        acc[4 + m][n] = __builtin_amdgcn_mfma_f32_16x16x32_bf16(af2_[m], bf_[n], acc[4 + m][n], 0, 0, 0); \
    __builtin_amdgcn_s_setprio(0);                                            \
    __builtin_amdgcn_s_barrier();                                             \
  } while (0)

  for (int u = 0; u < NU - 3; ++u) {   // u = 0..52, stages tile u+3
    if (s0 && u == 32) {               // base GEMM complete -> silu in registers
      #pragma unroll
      for (int m = 0; m < 8; ++m)
        #pragma unroll
        for (int n = 0; n < 4; ++n)
          #pragma unroll
          for (int j = 0; j < 4; ++j) {
            float v = acc[m][n][j];
            acc[m][n][j] = v / (1.0f + __expf(-v));
          }
    }
    PH0(u, true);
    PH1(u, true, 8);
  }
  PH0(53, false); PH1(53, false, 4);
  PH0(54, false); PH1(54, false, 0);
  PH0(55, false); PH1(55, false, 0);
#undef PH0
#undef PH1

  // plain stores: split 0 -> out, split s>0 -> partial P[s-1]
  float* dst = s0 ? out : (P + (size_t)(split - 1) * ((size_t)B_ROWS * O_DIM));
  #pragma unroll
  for (int m = 0; m < 8; ++m)
    #pragma unroll
    for (int n = 0; n < 4; ++n) {
      const size_t r0 = brow + wm * 128 + m * 16 + kg * 4;
      const size_t c  = bcol + wn * 64 + n * 16 + rr;
      #pragma unroll
      for (int j = 0; j < 4; ++j)
        dst[(r0 + j) * O_DIM + c] = acc[m][n][j];
    }
}

// ---- final: out += P0 + P1 + P2 (float4) ----
__global__ void k_reduce(float* __restrict__ out, const float* __restrict__ P) {
  const size_t i = (size_t)blockIdx.x * 256 + threadIdx.x;
  const size_t NE = (size_t)B_ROWS * O_DIM / 4;
  float4 a = ((const float4*)out)[i];
  float4 b = ((const float4*)P)[i];
  float4 c = ((const float4*)P)[i + NE];
  float4 d = ((const float4*)P)[i + 2 * NE];
  a.x += b.x + c.x + d.x;  a.y += b.y + c.y + d.y;
  a.z += b.z + c.z + d.z;  a.w += b.w + c.w + d.w;
  ((float4*)out)[i] = a;
}

extern "C" void kernel_launch(void* const* d_in, const int* in_sizes, int n_in,
                              void* d_out, int out_size, void* d_ws, size_t ws_size,
                              hipStream_t stream) {
  const float* x  = (const float*)d_in[0];   // [4096][1024]
  const float* bw = (const float*)d_in[1];   // [1024][1024]
  const float* lw = (const float*)d_in[2];   // [1024][1024][6]
  float* out = (float*)d_out;                // [4096][1024]

  char* w = (char*)d_ws;
  u16*  Ab = (u16*)(w);                                  //  8 MiB [4096][1024]
  u16*  Al = (u16*)(w + (size_t)8   * 1024 * 1024);      // 48 MiB [4096][6144]
  u16*  Bb = (u16*)(w + (size_t)56  * 1024 * 1024);      //  2 MiB [1024][1024]
  u16*  Bl = (u16*)(w + (size_t)58  * 1024 * 1024);      // 12 MiB [1024][6144]
  float* P = (float*)(w + (size_t)72 * 1024 * 1024);     // 48 MiB: 3 x [4096][1024] f32

  hipFuncSetAttribute((const void*)k_gemm,
                      hipFuncAttributeMaxDynamicSharedMemorySize, LDS_BYTES);

  k_prep_w    <<<dim3(2048), 256, 0, stream>>>(bw, lw, Bb, Bl);
  k_prep_basis<<<dim3(B_ROWS), 256, 0, stream>>>(x, Ab, Al);
  k_gemm      <<<dim3(4 * (B_ROWS / BM) * (O_DIM / BN)), 512, LDS_BYTES, stream>>>(Ab, Bb, Al, Bl, out, P);
  k_reduce    <<<dim3((B_ROWS * O_DIM / 4) / 256), 256, 0, stream>>>(out, P);
}